// Round 1
// baseline (187.467 us; speedup 1.0000x reference)
//
#include <hip/hip_runtime.h>
#include <math.h>

#define BATCH 4096
#define DIM 256
#define FPC 8
#define NPAIR 14336   // 512 blocks * C(8,2)
#define SHIFT 22.0f

// ---------------------------------------------------------------------------
// ws layout (floats): [0, 4096) = sq norms ; [4096, 8192) = S accumulators
// ---------------------------------------------------------------------------

__global__ __launch_bounds__(256) void sqnorm_kernel(const float* __restrict__ x,
                                                     float* __restrict__ sq) {
    int t = blockIdx.x * 256 + threadIdx.x;
    int row = t >> 6;
    int lane = t & 63;
    float4 v = ((const float4*)(x + row * DIM))[lane];
    float s = v.x * v.x + v.y * v.y + v.z * v.z + v.w * v.w;
#pragma unroll
    for (int off = 32; off > 0; off >>= 1) s += __shfl_xor(s, off);
    if (lane == 0) sq[row] = s;
}

// Fused x@x^T tile + dist + exp-sum (block-diagonal excluded) -> atomicAdd S[row]
__global__ __launch_bounds__(256) void dist_expsum_kernel(const float* __restrict__ x,
                                                          const float* __restrict__ sq,
                                                          float* __restrict__ S) {
    constexpr int BM = 128, BN = 128, BK = 8;
    __shared__ float As[BK][BM];  // [k][m] transposed for contiguous micro-tile reads
    __shared__ float Bs[BK][BN];

    const int tid = threadIdx.x;
    const int row0 = blockIdx.y * BM;
    const int col0 = blockIdx.x * BN;
    const int tr = tid >> 4;          // 0..15 thread-row
    const int tc = tid & 15;          // 0..15 thread-col
    const int lr = tid >> 1;          // 0..127 load row
    const int lk = (tid & 1) * 4;     // 0 or 4 load k-offset

    float acc[8][8];
#pragma unroll
    for (int i = 0; i < 8; i++)
#pragma unroll
        for (int j = 0; j < 8; j++) acc[i][j] = 0.f;

    for (int k0 = 0; k0 < DIM; k0 += BK) {
        float4 av = *(const float4*)(x + (row0 + lr) * DIM + k0 + lk);
        float4 bv = *(const float4*)(x + (col0 + lr) * DIM + k0 + lk);
        __syncthreads();
        As[lk + 0][lr] = av.x; As[lk + 1][lr] = av.y;
        As[lk + 2][lr] = av.z; As[lk + 3][lr] = av.w;
        Bs[lk + 0][lr] = bv.x; Bs[lk + 1][lr] = bv.y;
        Bs[lk + 2][lr] = bv.z; Bs[lk + 3][lr] = bv.w;
        __syncthreads();
#pragma unroll
        for (int kk = 0; kk < BK; kk++) {
            float a[8], b[8];
            *(float4*)&a[0] = *(const float4*)&As[kk][tr * 8];
            *(float4*)&a[4] = *(const float4*)&As[kk][tr * 8 + 4];
            *(float4*)&b[0] = *(const float4*)&Bs[kk][tc * 8];
            *(float4*)&b[4] = *(const float4*)&Bs[kk][tc * 8 + 4];
#pragma unroll
            for (int i = 0; i < 8; i++)
#pragma unroll
                for (int j = 0; j < 8; j++)
                    acc[i][j] = fmaf(a[i], b[j], acc[i][j]);
        }
    }

    // epilogue: dist -> exp(dist - SHIFT), exclude same-8-block cols
    float sqr[8], sqc[8];
#pragma unroll
    for (int i = 0; i < 8; i++) sqr[i] = sq[row0 + tr * 8 + i];
#pragma unroll
    for (int j = 0; j < 8; j++) sqc[j] = sq[col0 + tc * 8 + j];

    const bool diag = (row0 == col0);   // 8-blocks never straddle 128-tiles
    float rsum[8];
#pragma unroll
    for (int i = 0; i < 8; i++) {
        int r = row0 + tr * 8 + i;
        float s = 0.f;
#pragma unroll
        for (int j = 0; j < 8; j++) {
            int c = col0 + tc * 8 + j;
            float d2 = sqr[i] - 2.f * acc[i][j] + sqc[j];
            float dd = sqrtf(fmaxf(d2, 0.f));
            float e = __expf(dd - SHIFT);
            if (diag && ((r >> 3) == (c >> 3))) e = 0.f;
            s += e;
        }
        rsum[i] = s;
    }
    // reduce across the 16 threads sharing tr (they are contiguous lanes in a wave)
#pragma unroll
    for (int i = 0; i < 8; i++) {
#pragma unroll
        for (int m = 1; m < 16; m <<= 1) rsum[i] += __shfl_xor(rsum[i], m);
    }
    if (tc == 0) {
#pragma unroll
        for (int i = 0; i < 8; i++) atomicAdd(&S[row0 + tr * 8 + i], rsum[i]);
    }
}

// Per 8-block: 28 within-block distances -> nll -> mean contribution
__global__ __launch_bounds__(64) void pairs_kernel(const float* __restrict__ x,
                                                   const float* __restrict__ S,
                                                   float* __restrict__ out) {
    __shared__ float xs[FPC][DIM + 4];  // +4 pad: distinct banks for distinct rows
    const int base = blockIdx.x * FPC;
    const int lane = threadIdx.x;
#pragma unroll
    for (int r = 0; r < FPC; r++) {
        ((float4*)&xs[r][0])[lane] = ((const float4*)(x + (base + r) * DIM))[lane];
    }
    __syncthreads();

    float nll = 0.f;
    if (lane < 28) {
        int p = lane, a = 0;
        while (p >= 7 - a) { p -= 7 - a; a++; }
        int b = a + 1 + p;   // a < b, anchor = a (row < i in reference)
        float d2 = 0.f;
        for (int k = 0; k < DIM; k++) {
            float df = xs[a][k] - xs[b][k];
            d2 = fmaf(df, df, d2);
        }
        float dd = sqrtf(fmaxf(d2, 0.f));
        float lse = SHIFT + logf(S[base + a] + __expf(dd - SHIFT));
        nll = lse - dd;
    }
#pragma unroll
    for (int off = 32; off > 0; off >>= 1) nll += __shfl_xor(nll, off);
    if (lane == 0) atomicAdd(out, nll * (1.0f / (float)NPAIR));
}

extern "C" void kernel_launch(void* const* d_in, const int* in_sizes, int n_in,
                              void* d_out, int out_size, void* d_ws, size_t ws_size,
                              hipStream_t stream) {
    const float* x = (const float*)d_in[0];
    float* sq = (float*)d_ws;
    float* S  = sq + BATCH;
    float* out = (float*)d_out;

    hipMemsetAsync(S, 0, BATCH * sizeof(float), stream);
    hipMemsetAsync(out, 0, sizeof(float), stream);

    sqnorm_kernel<<<BATCH * 64 / 256, 256, 0, stream>>>(x, sq);

    dim3 grid(BATCH / 128, BATCH / 128);
    dist_expsum_kernel<<<grid, 256, 0, stream>>>(x, sq, S);

    pairs_kernel<<<BATCH / FPC, 64, 0, stream>>>(x, S, out);
}

// Round 2
// 98.493 us; speedup vs baseline: 1.9033x; 1.9033x over previous
//
#include <hip/hip_runtime.h>
#include <math.h>

#define BATCH 4096
#define DIM 256
#define FPC 8
#define NPAIR 14336   // 512 blocks * C(8,2)
#define SHIFT 22.0f

typedef __bf16 bf16x8 __attribute__((ext_vector_type(8)));
typedef float  f32x4  __attribute__((ext_vector_type(4)));

// fp32 -> bf16 round-to-nearest-even (inputs are finite normals; no NaN path)
__device__ __forceinline__ unsigned short f2bf(float f) {
    unsigned int u = __float_as_uint(f);
    u += 0x7FFFu + ((u >> 16) & 1u);
    return (unsigned short)(u >> 16);
}

// async global->LDS, 16B per lane; dest = wave-uniform base + lane*16
__device__ __forceinline__ void g2l16(const void* g, void* l) {
    __builtin_amdgcn_global_load_lds((__attribute__((address_space(1))) void*)(g),
                                     (__attribute__((address_space(3))) void*)(l),
                                     16, 0, 0);
}

// ---------------------------------------------------------------------------
// ws layout: [0,4096) f32 sq ; [4096,8192) f32 S ; then 4096*256 bf16 (2 MB)
// ---------------------------------------------------------------------------

__global__ __launch_bounds__(256) void prep_kernel(const float* __restrict__ x,
                                                   float* __restrict__ sq,
                                                   float* __restrict__ S,
                                                   unsigned short* __restrict__ xb,
                                                   float* __restrict__ out) {
    int t = blockIdx.x * 256 + threadIdx.x;
    int row = t >> 6;
    int lane = t & 63;
    float4 v = ((const float4*)(x + row * DIM))[lane];
    ushort4 b;
    b.x = f2bf(v.x); b.y = f2bf(v.y); b.z = f2bf(v.z); b.w = f2bf(v.w);
    ((ushort4*)(xb + row * DIM))[lane] = b;
    float s = v.x * v.x + v.y * v.y + v.z * v.z + v.w * v.w;
#pragma unroll
    for (int off = 32; off > 0; off >>= 1) s += __shfl_xor(s, off);
    if (lane == 0) { sq[row] = s; S[row] = 0.f; }
    if (t == 0) out[0] = 0.f;
}

// 128x128 tile of dist = sqrt(sq_r - 2*X@X^T + sq_c); exp-sum rows into S,
// excluding same-8-block columns. bf16 MFMA 16x16x32, 4 waves of 64x64.
__global__ __launch_bounds__(256) void dist_expsum_mfma(const unsigned short* __restrict__ xb,
                                                        const float* __restrict__ sq,
                                                        float* __restrict__ S) {
    __shared__ unsigned short As[128][32];  // row-major, 64B rows
    __shared__ unsigned short Bs[128][32];

    const int tid  = threadIdx.x;
    const int w    = tid >> 6;      // wave 0..3
    const int lane = tid & 63;
    const int wr   = w >> 1;        // wave row 0..1 (64-row half)
    const int wc   = w & 1;         // wave col 0..1
    const int quad = lane >> 4;     // 0..3
    const int lcol = lane & 15;     // 0..15
    const int row0 = blockIdx.y * 128;
    const int col0 = blockIdx.x * 128;

    f32x4 acc[4][4];
#pragma unroll
    for (int i = 0; i < 4; i++)
#pragma unroll
        for (int j = 0; j < 4; j++) {
            f32x4 z = {0.f, 0.f, 0.f, 0.f};
            acc[i][j] = z;
        }

    const int lrow = lane >> 2;        // 0..15: row within 16-row chunk
    const int lchk = (lane & 3) * 8;   // bf16 element offset within row

    for (int k0 = 0; k0 < DIM; k0 += 32) {
        __syncthreads();   // previous compute done before overwrite
        // wave w stages A rows [w*32, w*32+32) and B rows likewise
        g2l16(xb + (size_t)(row0 + w * 32      + lrow) * DIM + k0 + lchk, &As[w * 32      + lrow][lchk]);
        g2l16(xb + (size_t)(row0 + w * 32 + 16 + lrow) * DIM + k0 + lchk, &As[w * 32 + 16 + lrow][lchk]);
        g2l16(xb + (size_t)(col0 + w * 32      + lrow) * DIM + k0 + lchk, &Bs[w * 32      + lrow][lchk]);
        g2l16(xb + (size_t)(col0 + w * 32 + 16 + lrow) * DIM + k0 + lchk, &Bs[w * 32 + 16 + lrow][lchk]);
        __syncthreads();   // drains vmcnt before LDS reads

        bf16x8 a[4], b[4];
#pragma unroll
        for (int i = 0; i < 4; i++)
            a[i] = *(const bf16x8*)&As[wr * 64 + i * 16 + lcol][quad * 8];
#pragma unroll
        for (int j = 0; j < 4; j++)
            b[j] = *(const bf16x8*)&Bs[wc * 64 + j * 16 + lcol][quad * 8];
#pragma unroll
        for (int i = 0; i < 4; i++)
#pragma unroll
            for (int j = 0; j < 4; j++)
                acc[i][j] = __builtin_amdgcn_mfma_f32_16x16x32_bf16(a[i], b[j], acc[i][j], 0, 0, 0);
    }

    // epilogue: C/D layout col=lane&15, row=quad*4+reg
    const bool diagblk = (blockIdx.x == blockIdx.y);
#pragma unroll
    for (int i = 0; i < 4; i++) {
        const int rbase = row0 + wr * 64 + i * 16 + quad * 4;
        const float4 s4 = *(const float4*)(sq + rbase);
        const float sr[4] = {s4.x, s4.y, s4.z, s4.w};
        float rs[4] = {0.f, 0.f, 0.f, 0.f};
#pragma unroll
        for (int j = 0; j < 4; j++) {
            const int c = col0 + wc * 64 + j * 16 + lcol;
            const float sc = sq[c];
            const bool extile = diagblk && (wr * 4 + i == wc * 4 + j);
#pragma unroll
            for (int r = 0; r < 4; r++) {
                float d2 = sr[r] + sc - 2.f * acc[i][j][r];
                float dd = sqrtf(fmaxf(d2, 0.f));
                float e = __expf(dd - SHIFT);
                if (extile && (((quad * 4 + r) >> 3) == (lcol >> 3))) e = 0.f;
                rs[r] += e;
            }
        }
        // sum across the 16 lanes of this quad (they hold the 16 cols... of 64)
#pragma unroll
        for (int m = 1; m < 16; m <<= 1) {
#pragma unroll
            for (int r = 0; r < 4; r++) rs[r] += __shfl_xor(rs[r], m);
        }
        if (lcol == 0) {
#pragma unroll
            for (int r = 0; r < 4; r++) atomicAdd(&S[rbase + r], rs[r]);
        }
    }
}

// per 8-block: 28 within-block fp32 distances -> nll -> one atomic per block
__global__ __launch_bounds__(256) void pairs_kernel(const float* __restrict__ x,
                                                    const float* __restrict__ S,
                                                    float* __restrict__ out) {
    __shared__ float wsum[4];
    const int tid = threadIdx.x;
    const int p = tid >> 3;     // pair id 0..31 (28 used)
    const int g = tid & 7;      // lane within pair group
    const int base = blockIdx.x * FPC;

    float nll = 0.f;
    if (p < 28) {
        int a = 0, q = p;
        while (q >= 7 - a) { q -= 7 - a; a++; }
        const int b = a + 1 + q;                    // anchor=a, positive=b
        const float4* xa  = (const float4*)(x + (size_t)(base + a) * DIM);
        const float4* xbp = (const float4*)(x + (size_t)(base + b) * DIM);
        float d2 = 0.f;
#pragma unroll
        for (int r = 0; r < 8; r++) {
            float4 va = xa[r * 8 + g], vb = xbp[r * 8 + g];
            float dx = va.x - vb.x, dy = va.y - vb.y;
            float dz = va.z - vb.z, dw = va.w - vb.w;
            d2 = fmaf(dx, dx, d2); d2 = fmaf(dy, dy, d2);
            d2 = fmaf(dz, dz, d2); d2 = fmaf(dw, dw, d2);
        }
        d2 += __shfl_xor(d2, 1);
        d2 += __shfl_xor(d2, 2);
        d2 += __shfl_xor(d2, 4);
        if (g == 0) {
            float dd = sqrtf(fmaxf(d2, 0.f));
            nll = SHIFT + logf(S[base + a] + __expf(dd - SHIFT)) - dd;
        }
    }
#pragma unroll
    for (int off = 1; off < 64; off <<= 1) nll += __shfl_xor(nll, off);
    if ((tid & 63) == 0) wsum[tid >> 6] = nll;
    __syncthreads();
    if (tid == 0)
        atomicAdd(out, (wsum[0] + wsum[1] + wsum[2] + wsum[3]) * (1.0f / (float)NPAIR));
}

extern "C" void kernel_launch(void* const* d_in, const int* in_sizes, int n_in,
                              void* d_out, int out_size, void* d_ws, size_t ws_size,
                              hipStream_t stream) {
    const float* x = (const float*)d_in[0];
    float* sq = (float*)d_ws;
    float* S  = sq + BATCH;
    unsigned short* xb = (unsigned short*)(S + BATCH);
    float* out = (float*)d_out;

    prep_kernel<<<BATCH * 64 / 256, 256, 0, stream>>>(x, sq, S, xb, out);

    dim3 grid(BATCH / 128, BATCH / 128);
    dist_expsum_mfma<<<grid, 256, 0, stream>>>(xb, sq, S);

    pairs_kernel<<<BATCH / FPC, 256, 0, stream>>>(x, S, out);
}

// Round 4
// 90.479 us; speedup vs baseline: 2.0719x; 1.0886x over previous
//
#include <hip/hip_runtime.h>
#include <math.h>

#define BATCH 4096
#define DIM 256
#define FPC 8
#define NPAIR 14336   // 512 blocks * C(8,2)
#define SHIFT 22.0f

typedef __bf16 bf16x8 __attribute__((ext_vector_type(8)));
typedef float  f32x4  __attribute__((ext_vector_type(4)));

// fp32 -> bf16 round-to-nearest-even (inputs are finite normals; no NaN path)
__device__ __forceinline__ unsigned short f2bf(float f) {
    unsigned int u = __float_as_uint(f);
    u += 0x7FFFu + ((u >> 16) & 1u);
    return (unsigned short)(u >> 16);
}

// async global->LDS, 16B per lane; dest = wave-uniform base + lane*16
__device__ __forceinline__ void g2l16(const void* g, void* l) {
    __builtin_amdgcn_global_load_lds((__attribute__((address_space(1))) void*)(g),
                                     (__attribute__((address_space(3))) void*)(l),
                                     16, 0, 0);
}

// ---------------------------------------------------------------------------
// ws layout: [0,4096) f32 sq ; [4096,8192) f32 S ; then 4096*256 bf16 (2 MB)
// ---------------------------------------------------------------------------

__global__ __launch_bounds__(256) void prep_kernel(const float* __restrict__ x,
                                                   float* __restrict__ sq,
                                                   float* __restrict__ S,
                                                   unsigned short* __restrict__ xb,
                                                   float* __restrict__ out) {
    int t = blockIdx.x * 256 + threadIdx.x;
    int row = t >> 6;
    int lane = t & 63;
    float4 v = ((const float4*)(x + row * DIM))[lane];
    ushort4 b;
    b.x = f2bf(v.x); b.y = f2bf(v.y); b.z = f2bf(v.z); b.w = f2bf(v.w);
    ((ushort4*)(xb + row * DIM))[lane] = b;
    float s = v.x * v.x + v.y * v.y + v.z * v.z + v.w * v.w;
#pragma unroll
    for (int off = 32; off > 0; off >>= 1) s += __shfl_xor(s, off);
    if (lane == 0) { sq[row] = s; S[row] = 0.f; }
    if (t == 0) out[0] = 0.f;
}

// Upper-triangular 128x128 tile of dist = sqrt(sq_r - 2*X@X^T + sq_c).
// Row exp-sums -> S[row]; for off-diagonal tiles also column exp-sums -> S[col]
// (symmetry). Same-8-block pairs excluded (only possible on diagonal tiles).
__global__ __launch_bounds__(256) void dist_expsum_mfma(const unsigned short* __restrict__ xb,
                                                        const float* __restrict__ sq,
                                                        float* __restrict__ S) {
    __shared__ unsigned short As[128][32];  // row-major, 64B rows
    __shared__ unsigned short Bs[128][32];

    // triangular decode: tile (bi, bj) with bi <= bj
    int t = blockIdx.x, bi = 0;
    while (t >= 32 - bi) { t -= 32 - bi; bi++; }
    const int bj = bi + t;
    const int row0 = bi * 128;
    const int col0 = bj * 128;
    const bool diagblk = (bi == bj);

    const int tid  = threadIdx.x;
    const int w    = tid >> 6;      // wave 0..3
    const int lane = tid & 63;
    const int wr   = w >> 1;        // wave row 0..1 (64-row half)
    const int wc   = w & 1;         // wave col 0..1
    const int quad = lane >> 4;     // 0..3
    const int lcol = lane & 15;     // 0..15

    f32x4 acc[4][4];
#pragma unroll
    for (int i = 0; i < 4; i++)
#pragma unroll
        for (int j = 0; j < 4; j++) {
            f32x4 z = {0.f, 0.f, 0.f, 0.f};
            acc[i][j] = z;
        }

    const int lrow = lane >> 2;        // 0..15: row within 16-row chunk
    const int lchk = (lane & 3) * 8;   // bf16 element offset within row

    for (int k0 = 0; k0 < DIM; k0 += 32) {
        __syncthreads();   // previous compute done before overwrite
        g2l16(xb + (size_t)(row0 + w * 32      + lrow) * DIM + k0 + lchk, &As[w * 32      + lrow][lchk]);
        g2l16(xb + (size_t)(row0 + w * 32 + 16 + lrow) * DIM + k0 + lchk, &As[w * 32 + 16 + lrow][lchk]);
        g2l16(xb + (size_t)(col0 + w * 32      + lrow) * DIM + k0 + lchk, &Bs[w * 32      + lrow][lchk]);
        g2l16(xb + (size_t)(col0 + w * 32 + 16 + lrow) * DIM + k0 + lchk, &Bs[w * 32 + 16 + lrow][lchk]);
        __syncthreads();   // drains vmcnt before LDS reads

        bf16x8 a[4], b[4];
#pragma unroll
        for (int i = 0; i < 4; i++)
            a[i] = *(const bf16x8*)&As[wr * 64 + i * 16 + lcol][quad * 8];
#pragma unroll
        for (int j = 0; j < 4; j++)
            b[j] = *(const bf16x8*)&Bs[wc * 64 + j * 16 + lcol][quad * 8];
#pragma unroll
        for (int i = 0; i < 4; i++)
#pragma unroll
            for (int j = 0; j < 4; j++)
                acc[i][j] = __builtin_amdgcn_mfma_f32_16x16x32_bf16(a[i], b[j], acc[i][j], 0, 0, 0);
    }

    // epilogue: C/D layout col=lane&15, row=quad*4+reg
    float sc[4];
#pragma unroll
    for (int j = 0; j < 4; j++) sc[j] = sq[col0 + wc * 64 + j * 16 + lcol];

    float cs[4] = {0.f, 0.f, 0.f, 0.f};   // per-lane column partial sums

#pragma unroll
    for (int i = 0; i < 4; i++) {
        const int rbase = row0 + wr * 64 + i * 16 + quad * 4;
        const float4 s4 = *(const float4*)(sq + rbase);
        const float sr[4] = {s4.x, s4.y, s4.z, s4.w};
        float rs[4] = {0.f, 0.f, 0.f, 0.f};
#pragma unroll
        for (int j = 0; j < 4; j++) {
            const bool extile = diagblk && (wr * 4 + i == wc * 4 + j);
            float csj = 0.f;
#pragma unroll
            for (int r = 0; r < 4; r++) {
                float d2 = sr[r] + sc[j] - 2.f * acc[i][j][r];
                float dd = sqrtf(fmaxf(d2, 0.f));
                float e = __expf(dd - SHIFT);
                if (extile && (((quad * 4 + r) >> 3) == (lcol >> 3))) e = 0.f;
                rs[r] += e;
                csj += e;
            }
            cs[j] += csj;
        }
        // row sums: reduce across the 16 lanes of this quad
#pragma unroll
        for (int m = 1; m < 16; m <<= 1) {
#pragma unroll
            for (int r = 0; r < 4; r++) rs[r] += __shfl_xor(rs[r], m);
        }
        if (lcol == 0) {
#pragma unroll
            for (int r = 0; r < 4; r++) atomicAdd(&S[rbase + r], rs[r]);
        }
    }

    if (!diagblk) {
        // column sums: reduce across quads (stride 16, 32), lanes 0..15 hold cols
#pragma unroll
        for (int j = 0; j < 4; j++) {
            cs[j] += __shfl_xor(cs[j], 16);
            cs[j] += __shfl_xor(cs[j], 32);
        }
        if (lane < 16) {
#pragma unroll
            for (int j = 0; j < 4; j++)
                atomicAdd(&S[col0 + wc * 64 + j * 16 + lane], cs[j]);
        }
    }
}

// per 8-block: 28 within-block fp32 distances -> nll -> one atomic per block
__global__ __launch_bounds__(256) void pairs_kernel(const float* __restrict__ x,
                                                    const float* __restrict__ S,
                                                    float* __restrict__ out) {
    __shared__ float wsum[4];
    const int tid = threadIdx.x;
    const int p = tid >> 3;     // pair id 0..31 (28 used)
    const int g = tid & 7;      // lane within pair group
    const int base = blockIdx.x * FPC;

    float nll = 0.f;
    if (p < 28) {
        int a = 0, q = p;
        while (q >= 7 - a) { q -= 7 - a; a++; }
        const int b = a + 1 + q;                    // anchor=a, positive=b
        const float4* xa  = (const float4*)(x + (size_t)(base + a) * DIM);
        const float4* xbp = (const float4*)(x + (size_t)(base + b) * DIM);
        float d2 = 0.f;
#pragma unroll
        for (int r = 0; r < 8; r++) {
            float4 va = xa[r * 8 + g], vb = xbp[r * 8 + g];
            float dx = va.x - vb.x, dy = va.y - vb.y;
            float dz = va.z - vb.z, dw = va.w - vb.w;
            d2 = fmaf(dx, dx, d2); d2 = fmaf(dy, dy, d2);
            d2 = fmaf(dz, dz, d2); d2 = fmaf(dw, dw, d2);
        }
        d2 += __shfl_xor(d2, 1);
        d2 += __shfl_xor(d2, 2);
        d2 += __shfl_xor(d2, 4);
        if (g == 0) {
            float dd = sqrtf(fmaxf(d2, 0.f));
            nll = SHIFT + __logf(S[base + a] + __expf(dd - SHIFT)) - dd;
        }
    }
#pragma unroll
    for (int off = 1; off < 64; off <<= 1) nll += __shfl_xor(nll, off);
    if ((tid & 63) == 0) wsum[tid >> 6] = nll;
    __syncthreads();
    if (tid == 0)
        atomicAdd(out, (wsum[0] + wsum[1] + wsum[2] + wsum[3]) * (1.0f / (float)NPAIR));
}

extern "C" void kernel_launch(void* const* d_in, const int* in_sizes, int n_in,
                              void* d_out, int out_size, void* d_ws, size_t ws_size,
                              hipStream_t stream) {
    const float* x = (const float*)d_in[0];
    float* sq = (float*)d_ws;
    float* S  = sq + BATCH;
    unsigned short* xb = (unsigned short*)(S + BATCH);
    float* out = (float*)d_out;

    prep_kernel<<<BATCH * 64 / 256, 256, 0, stream>>>(x, sq, S, xb, out);

    dist_expsum_mfma<<<528, 256, 0, stream>>>(xb, sq, S);

    pairs_kernel<<<BATCH / FPC, 256, 0, stream>>>(x, S, out);
}

// Round 5
// 89.015 us; speedup vs baseline: 2.1060x; 1.0165x over previous
//
#include <hip/hip_runtime.h>
#include <math.h>

#define BATCH 4096
#define DIM 256
#define FPC 8
#define NPAIR 14336   // 512 blocks * C(8,2)
#define SHIFT 22.0f

typedef __bf16 bf16x8 __attribute__((ext_vector_type(8)));
typedef float  f32x4  __attribute__((ext_vector_type(4)));

// fp32 -> bf16 round-to-nearest-even (inputs are finite normals; no NaN path)
__device__ __forceinline__ unsigned short f2bf(float f) {
    unsigned int u = __float_as_uint(f);
    u += 0x7FFFu + ((u >> 16) & 1u);
    return (unsigned short)(u >> 16);
}

// async global->LDS, 16B per lane; dest = wave-uniform base + lane*16
__device__ __forceinline__ void g2l16(const void* g, void* l) {
    __builtin_amdgcn_global_load_lds((__attribute__((address_space(1))) void*)(g),
                                     (__attribute__((address_space(3))) void*)(l),
                                     16, 0, 0);
}

// ---------------------------------------------------------------------------
// ws layout: [0,4096) f32 sq ; [4096,8192) f32 S ; then 4096*256 bf16 (2 MB)
// ---------------------------------------------------------------------------

__global__ __launch_bounds__(256) void prep_kernel(const float* __restrict__ x,
                                                   float* __restrict__ sq,
                                                   float* __restrict__ S,
                                                   unsigned short* __restrict__ xb,
                                                   float* __restrict__ out) {
    int t = blockIdx.x * 256 + threadIdx.x;
    int row = t >> 6;
    int lane = t & 63;
    float4 v = ((const float4*)(x + row * DIM))[lane];
    ushort4 b;
    b.x = f2bf(v.x); b.y = f2bf(v.y); b.z = f2bf(v.z); b.w = f2bf(v.w);
    ((ushort4*)(xb + row * DIM))[lane] = b;
    float s = v.x * v.x + v.y * v.y + v.z * v.z + v.w * v.w;
#pragma unroll
    for (int off = 32; off > 0; off >>= 1) s += __shfl_xor(s, off);
    if (lane == 0) { sq[row] = s; S[row] = 0.f; }
    if (t == 0) out[0] = 0.f;
}

// Upper-triangular 128x128 tile of dist = sqrt(sq_r - 2*X@X^T + sq_c).
// Row exp-sums -> S[row]; off-diagonal tiles also column exp-sums -> S[col].
// LDS chunk-XOR swizzle: slot (r, c') holds global 16B-chunk c' ^ ((r>>1)&3),
// so fragment reads hit 8 distinct bank groups (2-way aliasing = free) while
// global_load_lds keeps its mandatory linear base+lane*16 LDS mapping.
__global__ __launch_bounds__(256) void dist_expsum_mfma(const unsigned short* __restrict__ xb,
                                                        const float* __restrict__ sq,
                                                        float* __restrict__ S) {
    __shared__ unsigned short As[128][32];  // 64B rows, 4 chunks of 16B
    __shared__ unsigned short Bs[128][32];

    // triangular decode: tile (bi, bj) with bi <= bj
    int t = blockIdx.x, bi = 0;
    while (t >= 32 - bi) { t -= 32 - bi; bi++; }
    const int bj = bi + t;
    const int row0 = bi * 128;
    const int col0 = bj * 128;
    const bool diagblk = (bi == bj);

    const int tid  = threadIdx.x;
    const int w    = tid >> 6;      // wave 0..3
    const int lane = tid & 63;
    const int wr   = w >> 1;        // wave row 0..1 (64-row half)
    const int wc   = w & 1;         // wave col 0..1
    const int quad = lane >> 4;     // 0..3
    const int lcol = lane & 15;     // 0..15

    f32x4 acc[4][4];
#pragma unroll
    for (int i = 0; i < 4; i++)
#pragma unroll
        for (int j = 0; j < 4; j++) {
            f32x4 z = {0.f, 0.f, 0.f, 0.f};
            acc[i][j] = z;
        }

    // staging: one g2l16 = 16 rows x 64B. LDS slot = linear lane*16.
    const int lrow = lane >> 2;                          // row within 16-row call
    const int lchk = (lane & 3) * 8;                     // LDS slot chunk (linear!)
    const int gchk = ((lane & 3) ^ ((lrow >> 1) & 3)) * 8;  // swizzled global chunk
    // fragment read: slot chunk = quad ^ ((lcol>>1)&3)
    const int rchk = (quad ^ ((lcol >> 1) & 3)) * 8;

    for (int k0 = 0; k0 < DIM; k0 += 32) {
        __syncthreads();   // previous compute done before overwrite
        g2l16(xb + (size_t)(row0 + w * 32      + lrow) * DIM + k0 + gchk, &As[w * 32      + lrow][lchk]);
        g2l16(xb + (size_t)(row0 + w * 32 + 16 + lrow) * DIM + k0 + gchk, &As[w * 32 + 16 + lrow][lchk]);
        g2l16(xb + (size_t)(col0 + w * 32      + lrow) * DIM + k0 + gchk, &Bs[w * 32      + lrow][lchk]);
        g2l16(xb + (size_t)(col0 + w * 32 + 16 + lrow) * DIM + k0 + gchk, &Bs[w * 32 + 16 + lrow][lchk]);
        __syncthreads();   // drains vmcnt before LDS reads

        bf16x8 a[4], b[4];
#pragma unroll
        for (int i = 0; i < 4; i++)
            a[i] = *(const bf16x8*)&As[wr * 64 + i * 16 + lcol][rchk];
#pragma unroll
        for (int j = 0; j < 4; j++)
            b[j] = *(const bf16x8*)&Bs[wc * 64 + j * 16 + lcol][rchk];
#pragma unroll
        for (int i = 0; i < 4; i++)
#pragma unroll
            for (int j = 0; j < 4; j++)
                acc[i][j] = __builtin_amdgcn_mfma_f32_16x16x32_bf16(a[i], b[j], acc[i][j], 0, 0, 0);
    }

    // epilogue: C/D layout col=lane&15, row=quad*4+reg
    float sc[4];
#pragma unroll
    for (int j = 0; j < 4; j++) sc[j] = sq[col0 + wc * 64 + j * 16 + lcol];

    float cs[4] = {0.f, 0.f, 0.f, 0.f};   // per-lane column partial sums

#pragma unroll
    for (int i = 0; i < 4; i++) {
        const int rbase = row0 + wr * 64 + i * 16 + quad * 4;
        const float4 s4 = *(const float4*)(sq + rbase);
        const float sr[4] = {s4.x, s4.y, s4.z, s4.w};
        float rs[4] = {0.f, 0.f, 0.f, 0.f};
#pragma unroll
        for (int j = 0; j < 4; j++) {
            const bool extile = diagblk && (wr * 4 + i == wc * 4 + j);
            float csj = 0.f;
#pragma unroll
            for (int r = 0; r < 4; r++) {
                float d2 = sr[r] + sc[j] - 2.f * acc[i][j][r];
                float dd = sqrtf(fmaxf(d2, 0.f));
                float e = __expf(dd - SHIFT);
                if (extile && (((quad * 4 + r) >> 3) == (lcol >> 3))) e = 0.f;
                rs[r] += e;
                csj += e;
            }
            cs[j] += csj;
        }
        // row sums: reduce across the 16 lanes of this quad
#pragma unroll
        for (int m = 1; m < 16; m <<= 1) {
#pragma unroll
            for (int r = 0; r < 4; r++) rs[r] += __shfl_xor(rs[r], m);
        }
        if (lcol == 0) {
#pragma unroll
            for (int r = 0; r < 4; r++) atomicAdd(&S[rbase + r], rs[r]);
        }
    }

    if (!diagblk) {
        // column sums: reduce across quads (stride 16, 32), lanes 0..15 hold cols
#pragma unroll
        for (int j = 0; j < 4; j++) {
            cs[j] += __shfl_xor(cs[j], 16);
            cs[j] += __shfl_xor(cs[j], 32);
        }
        if (lane < 16) {
#pragma unroll
            for (int j = 0; j < 4; j++)
                atomicAdd(&S[col0 + wc * 64 + j * 16 + lane], cs[j]);
        }
    }
}

// per 8-block: 28 within-block fp32 distances -> nll -> one atomic per block
__global__ __launch_bounds__(256) void pairs_kernel(const float* __restrict__ x,
                                                    const float* __restrict__ S,
                                                    float* __restrict__ out) {
    __shared__ float wsum[4];
    const int tid = threadIdx.x;
    const int p = tid >> 3;     // pair id 0..31 (28 used)
    const int g = tid & 7;      // lane within pair group
    const int base = blockIdx.x * FPC;

    float nll = 0.f;
    if (p < 28) {
        int a = 0, q = p;
        while (q >= 7 - a) { q -= 7 - a; a++; }
        const int b = a + 1 + q;                    // anchor=a, positive=b
        const float4* xa  = (const float4*)(x + (size_t)(base + a) * DIM);
        const float4* xbp = (const float4*)(x + (size_t)(base + b) * DIM);
        float d2 = 0.f;
#pragma unroll
        for (int r = 0; r < 8; r++) {
            float4 va = xa[r * 8 + g], vb = xbp[r * 8 + g];
            float dx = va.x - vb.x, dy = va.y - vb.y;
            float dz = va.z - vb.z, dw = va.w - vb.w;
            d2 = fmaf(dx, dx, d2); d2 = fmaf(dy, dy, d2);
            d2 = fmaf(dz, dz, d2); d2 = fmaf(dw, dw, d2);
        }
        d2 += __shfl_xor(d2, 1);
        d2 += __shfl_xor(d2, 2);
        d2 += __shfl_xor(d2, 4);
        if (g == 0) {
            float dd = sqrtf(fmaxf(d2, 0.f));
            nll = SHIFT + __logf(S[base + a] + __expf(dd - SHIFT)) - dd;
        }
    }
#pragma unroll
    for (int off = 1; off < 64; off <<= 1) nll += __shfl_xor(nll, off);
    if ((tid & 63) == 0) wsum[tid >> 6] = nll;
    __syncthreads();
    if (tid == 0)
        atomicAdd(out, (wsum[0] + wsum[1] + wsum[2] + wsum[3]) * (1.0f / (float)NPAIR));
}

extern "C" void kernel_launch(void* const* d_in, const int* in_sizes, int n_in,
                              void* d_out, int out_size, void* d_ws, size_t ws_size,
                              hipStream_t stream) {
    const float* x = (const float*)d_in[0];
    float* sq = (float*)d_ws;
    float* S  = sq + BATCH;
    unsigned short* xb = (unsigned short*)(S + BATCH);
    float* out = (float*)d_out;

    prep_kernel<<<BATCH * 64 / 256, 256, 0, stream>>>(x, sq, S, xb, out);

    dist_expsum_mfma<<<528, 256, 0, stream>>>(xb, sq, S);

    pairs_kernel<<<BATCH / FPC, 256, 0, stream>>>(x, S, out);
}

// Round 6
// 87.125 us; speedup vs baseline: 2.1517x; 1.0217x over previous
//
#include <hip/hip_runtime.h>
#include <math.h>

#define BATCH 4096
#define DIM 256
#define FPC 8
#define NPAIR 14336   // 512 blocks * C(8,2)
#define SHIFT 22.0f

typedef __bf16 bf16x8 __attribute__((ext_vector_type(8)));
typedef float  f32x4  __attribute__((ext_vector_type(4)));

// fp32 -> bf16 round-to-nearest-even (inputs are finite normals; no NaN path)
__device__ __forceinline__ unsigned short f2bf(float f) {
    unsigned int u = __float_as_uint(f);
    u += 0x7FFFu + ((u >> 16) & 1u);
    return (unsigned short)(u >> 16);
}

// async global->LDS, 16B per lane; dest = wave-uniform base + lane*16
__device__ __forceinline__ void g2l16(const void* g, void* l) {
    __builtin_amdgcn_global_load_lds((__attribute__((address_space(1))) void*)(g),
                                     (__attribute__((address_space(3))) void*)(l),
                                     16, 0, 0);
}

// ---------------------------------------------------------------------------
// ws layout: [0,4096) f32 sq ; [4096,8192) f32 S ; then 4096*256 bf16 (2 MB)
// ---------------------------------------------------------------------------

__global__ __launch_bounds__(256) void prep_kernel(const float* __restrict__ x,
                                                   float* __restrict__ sq,
                                                   float* __restrict__ S,
                                                   unsigned short* __restrict__ xb,
                                                   float* __restrict__ out) {
    int t = blockIdx.x * 256 + threadIdx.x;
    int row = t >> 6;
    int lane = t & 63;
    float4 v = ((const float4*)(x + row * DIM))[lane];
    ushort4 b;
    b.x = f2bf(v.x); b.y = f2bf(v.y); b.z = f2bf(v.z); b.w = f2bf(v.w);
    ((ushort4*)(xb + row * DIM))[lane] = b;
    float s = v.x * v.x + v.y * v.y + v.z * v.z + v.w * v.w;
#pragma unroll
    for (int off = 32; off > 0; off >>= 1) s += __shfl_xor(s, off);
    if (lane == 0) { sq[row] = s; S[row] = 0.f; }
    if (t == 0) out[0] = 0.f;
}

// Upper-triangular 128x128 tile of dist = sqrt(sq_r - 2*X@X^T + sq_c).
// Row exp-sums -> S[row]; off-diagonal tiles also column exp-sums -> S[col].
// K staged in TWO 128-wide phases (64KB LDS) -> only 2 vmcnt drains per block
// (was 8). Chunk-XOR swizzle: global 16B-chunk g of row r lands in slot
// g ^ (r&15); reader slot (kk*4+quad) ^ lcol -> bank-balanced ds_read_b128
// while g2l16 keeps its mandatory linear base+lane*16 LDS mapping.
__global__ __launch_bounds__(256) void dist_expsum_mfma(const unsigned short* __restrict__ xb,
                                                        const float* __restrict__ sq,
                                                        float* __restrict__ S) {
    __shared__ unsigned short As[128][128];   // 32KB: 128 rows x 256B (16 chunks)
    __shared__ unsigned short Bs[128][128];   // 32KB

    // triangular decode: tile (bi, bj) with bi <= bj
    int t = blockIdx.x, bi = 0;
    while (t >= 32 - bi) { t -= 32 - bi; bi++; }
    const int bj = bi + t;
    const int row0 = bi * 128;
    const int col0 = bj * 128;
    const bool diagblk = (bi == bj);

    const int tid  = threadIdx.x;
    const int w    = tid >> 6;      // wave 0..3
    const int lane = tid & 63;
    const int wr   = w >> 1;        // wave row 0..1 (64-row half)
    const int wc   = w & 1;         // wave col 0..1
    const int quad = lane >> 4;     // 0..3
    const int lcol = lane & 15;     // 0..15

    f32x4 acc[4][4];
#pragma unroll
    for (int i = 0; i < 4; i++)
#pragma unroll
        for (int j = 0; j < 4; j++) {
            f32x4 z = {0.f, 0.f, 0.f, 0.f};
            acc[i][j] = z;
        }

    // staging: one g2l16 = 4 rows x 256B; lane covers (row lane>>4, chunk lane&15)
    const int lrow = lane >> 4;     // 0..3
    const int lchk = lane & 15;     // linear LDS slot chunk

    for (int ph = 0; ph < 2; ph++) {
        const int k0 = ph * 128;
        __syncthreads();   // previous phase's reads done before overwrite
#pragma unroll
        for (int c = 0; c < 8; c++) {
            const int rb = w * 32 + c * 4;          // wave w stages rows [w*32, w*32+32)
            const int r  = rb + lrow;
            const int gc = (lchk ^ (r & 15)) * 8;   // swizzled global chunk (elems)
            g2l16(xb + (size_t)(row0 + r) * DIM + k0 + gc,
                  (unsigned short*)&As[rb][0] + lane * 8);
            g2l16(xb + (size_t)(col0 + r) * DIM + k0 + gc,
                  (unsigned short*)&Bs[rb][0] + lane * 8);
        }
        __syncthreads();   // single vmcnt drain for 16 outstanding loads/wave

#pragma unroll
        for (int kk = 0; kk < 4; kk++) {
            const int slot = (((kk * 4 + quad) ^ lcol)) * 8;
            bf16x8 a[4], b[4];
#pragma unroll
            for (int i = 0; i < 4; i++)
                a[i] = *(const bf16x8*)&As[wr * 64 + i * 16 + lcol][slot];
#pragma unroll
            for (int j = 0; j < 4; j++)
                b[j] = *(const bf16x8*)&Bs[wc * 64 + j * 16 + lcol][slot];
#pragma unroll
            for (int i = 0; i < 4; i++)
#pragma unroll
                for (int j = 0; j < 4; j++)
                    acc[i][j] = __builtin_amdgcn_mfma_f32_16x16x32_bf16(a[i], b[j], acc[i][j], 0, 0, 0);
        }
    }

    // epilogue: C/D layout col=lane&15, row=quad*4+reg
    float sc[4];
#pragma unroll
    for (int j = 0; j < 4; j++) sc[j] = sq[col0 + wc * 64 + j * 16 + lcol];

    float cs[4] = {0.f, 0.f, 0.f, 0.f};   // per-lane column partial sums

#pragma unroll
    for (int i = 0; i < 4; i++) {
        const int rbase = row0 + wr * 64 + i * 16 + quad * 4;
        const float4 s4 = *(const float4*)(sq + rbase);
        const float sr[4] = {s4.x, s4.y, s4.z, s4.w};
        float rs[4] = {0.f, 0.f, 0.f, 0.f};
#pragma unroll
        for (int j = 0; j < 4; j++) {
            const bool extile = diagblk && (wr * 4 + i == wc * 4 + j);
            float csj = 0.f;
#pragma unroll
            for (int r = 0; r < 4; r++) {
                float d2 = sr[r] + sc[j] - 2.f * acc[i][j][r];
                float dd = sqrtf(fmaxf(d2, 0.f));
                float e = __expf(dd - SHIFT);
                if (extile && (((quad * 4 + r) >> 3) == (lcol >> 3))) e = 0.f;
                rs[r] += e;
                csj += e;
            }
            cs[j] += csj;
        }
        // row sums: reduce across the 16 lanes of this quad
#pragma unroll
        for (int m = 1; m < 16; m <<= 1) {
#pragma unroll
            for (int r = 0; r < 4; r++) rs[r] += __shfl_xor(rs[r], m);
        }
        if (lcol == 0) {
#pragma unroll
            for (int r = 0; r < 4; r++) atomicAdd(&S[rbase + r], rs[r]);
        }
    }

    if (!diagblk) {
        // column sums: reduce across quads (stride 16, 32), lanes 0..15 hold cols
#pragma unroll
        for (int j = 0; j < 4; j++) {
            cs[j] += __shfl_xor(cs[j], 16);
            cs[j] += __shfl_xor(cs[j], 32);
        }
        if (lane < 16) {
#pragma unroll
            for (int j = 0; j < 4; j++)
                atomicAdd(&S[col0 + wc * 64 + j * 16 + lane], cs[j]);
        }
    }
}

// per 8-block: 28 within-block fp32 distances -> nll -> one atomic per block
__global__ __launch_bounds__(256) void pairs_kernel(const float* __restrict__ x,
                                                    const float* __restrict__ S,
                                                    float* __restrict__ out) {
    __shared__ float wsum[4];
    const int tid = threadIdx.x;
    const int p = tid >> 3;     // pair id 0..31 (28 used)
    const int g = tid & 7;      // lane within pair group
    const int base = blockIdx.x * FPC;

    float nll = 0.f;
    if (p < 28) {
        int a = 0, q = p;
        while (q >= 7 - a) { q -= 7 - a; a++; }
        const int b = a + 1 + q;                    // anchor=a, positive=b
        const float4* xa  = (const float4*)(x + (size_t)(base + a) * DIM);
        const float4* xbp = (const float4*)(x + (size_t)(base + b) * DIM);
        float d2 = 0.f;
#pragma unroll
        for (int r = 0; r < 8; r++) {
            float4 va = xa[r * 8 + g], vb = xbp[r * 8 + g];
            float dx = va.x - vb.x, dy = va.y - vb.y;
            float dz = va.z - vb.z, dw = va.w - vb.w;
            d2 = fmaf(dx, dx, d2); d2 = fmaf(dy, dy, d2);
            d2 = fmaf(dz, dz, d2); d2 = fmaf(dw, dw, d2);
        }
        d2 += __shfl_xor(d2, 1);
        d2 += __shfl_xor(d2, 2);
        d2 += __shfl_xor(d2, 4);
        if (g == 0) {
            float dd = sqrtf(fmaxf(d2, 0.f));
            nll = SHIFT + __logf(S[base + a] + __expf(dd - SHIFT)) - dd;
        }
    }
#pragma unroll
    for (int off = 1; off < 64; off <<= 1) nll += __shfl_xor(nll, off);
    if ((tid & 63) == 0) wsum[tid >> 6] = nll;
    __syncthreads();
    if (tid == 0)
        atomicAdd(out, (wsum[0] + wsum[1] + wsum[2] + wsum[3]) * (1.0f / (float)NPAIR));
}

extern "C" void kernel_launch(void* const* d_in, const int* in_sizes, int n_in,
                              void* d_out, int out_size, void* d_ws, size_t ws_size,
                              hipStream_t stream) {
    const float* x = (const float*)d_in[0];
    float* sq = (float*)d_ws;
    float* S  = sq + BATCH;
    unsigned short* xb = (unsigned short*)(S + BATCH);
    float* out = (float*)d_out;

    prep_kernel<<<BATCH * 64 / 256, 256, 0, stream>>>(x, sq, S, xb, out);

    dist_expsum_mfma<<<528, 256, 0, stream>>>(xb, sq, S);

    pairs_kernel<<<BATCH / FPC, 256, 0, stream>>>(x, S, out);
}